// Round 1
// baseline (4919.022 us; speedup 1.0000x reference)
//
#include <hip/hip_runtime.h>

// Problem constants
#define B_ 64
#define T_ 512
#define DIN_ 256
#define N_ 1024
#define O_ 128

using half8 = __attribute__((ext_vector_type(8))) _Float16;
using f32x4 = __attribute__((ext_vector_type(4))) float;
typedef unsigned long long ull;

__device__ __forceinline__ half8 cvt8(float4 a, float4 b) {
    half8 h;
    h[0] = (_Float16)a.x; h[1] = (_Float16)a.y; h[2] = (_Float16)a.z; h[3] = (_Float16)a.w;
    h[4] = (_Float16)b.x; h[5] = (_Float16)b.y; h[6] = (_Float16)b.z; h[7] = (_Float16)b.w;
    return h;
}

__device__ __forceinline__ float fast_tanh(float x) {
    float ax = __builtin_fabsf(x);
    float e  = __expf(-2.0f * ax);
    float r  = __fdividef(1.0f - e, 1.0f + e);
    return x < 0.0f ? -r : r;
}

__device__ __forceinline__ unsigned pack2h(float a, float b) {
    union { _Float16 h; unsigned short s; } ha, hb;
    ha.h = (_Float16)a; hb.h = (_Float16)b;
    return (unsigned)ha.s | ((unsigned)hb.s << 16);
}

// ---------------------------------------------------------------------------
// Zero the exchange buffer: 4 bs x 2 parity x 8192 packets = 65536 ull.
// Tags==0 never match any wanted step (want >= 1), so prior-run / garbage
// contents can never be accepted as fresh.
// ---------------------------------------------------------------------------
__global__ void init_kernel(ull* exch) {
    exch[(ull)blockIdx.x * blockDim.x + threadIdx.x] = 0ull;
}

// ---------------------------------------------------------------------------
// Persistent recurrence: 32 blocks = 4 batch-slabs (bs) x 8 col-groups (cg).
// Block = 512 threads (8 waves), 16 batch rows x 128 cols; wave w owns 16 cols
// with its W slab (128 VGPRs fp16) + Win slab (32 VGPRs) register-resident.
//
// Exchange protocol (NEW): self-tagged 8B packets, no flags, no release drain.
//   packet = { fp16 val@even-col, fp16 val@odd-col, u32 tag = t }
// written with ONE 8B agent-scope atomic store, so tag+data are consistent.
// Producer: 1 shfl_xor pairs adjacent cols, 2 packet stores, then moves on —
// no vmcnt(0) drain, no flag publish. Consumer: spins directly on the data
// (loads pre-issued at the end of the previous iteration so they overlap the
// s_out + input-GEMM tail); a packet is consumable when its tag == t-1.
// Stability once fresh: block P writes step t+1 into a buffer only after P
// consumed step-t data from ALL cgs, which requires every block to have
// consumed step t-1 — so no location a consumer still wants can be
// overwritten. Same argument subsumes the intra-block LDS WAR hazard:
// seeing a wave's tag-t packets proves its step-t ds_reads completed, so
// staging t+1 into the LDS slab is safe without a trailing barrier.
// Packet index = half_index/2 of the MFMA A-fragment layout
// (addr_half = kb*512 + lane*8 + j), so consumer staging is: 16 coalesced 8B
// loads -> 16 linear u32 LDS writes -> raw (lgkmcnt-only) barrier ->
// ds_read_b128 A-fragments.
// ---------------------------------------------------------------------------
__global__ __launch_bounds__(512, 1) void rnn_kernel(
    const float* __restrict__ X,      // [B][T][DIN]
    const float* __restrict__ W,      // [N][N]
    const float* __restrict__ Win,    // [DIN][N]
    float* __restrict__ s_out,        // [B][T][N]
    ull* __restrict__ exch)           // [4][2][8192] packets
{
    const int bs   = blockIdx.x & 3;
    const int cg   = blockIdx.x >> 2;     // 0..7
    const int tid  = threadIdx.x;
    const int wave = tid >> 6;            // 0..7
    const int lane = tid & 63;
    const int l15  = lane & 15;
    const int quad = lane >> 4;
    const int col0 = cg * 128 + wave * 16;
    const int arow = bs * 16 + l15;       // A-frag batch row
    const int crow = bs * 16 + quad * 4;  // C-frag base batch row

    __shared__ _Float16 slab[16 * 1032];  // W/Win transpose staging + step slab

    // ---- one-time: W B-fragments (8 passes, one per wave)
    half8 wf[32];
    for (int p = 0; p < 8; ++p) {
        const int c = tid & 15, k0 = tid >> 4;
        const int wc = cg * 128 + p * 16 + c;
        for (int k = k0; k < N_; k += 32)
            slab[c * 1032 + k] = (_Float16)W[(size_t)k * N_ + wc];
        __syncthreads();
        if (wave == p) {
            #pragma unroll
            for (int kb = 0; kb < 32; ++kb)
                wf[kb] = *(const half8*)&slab[l15 * 1032 + kb * 32 + quad * 8];
        }
        __syncthreads();
    }
    // ---- one-time: Win B-fragments
    half8 winf[8];
    for (int p = 0; p < 8; ++p) {
        const int c = tid & 15, k0 = tid >> 4;
        const int wc = cg * 128 + p * 16 + c;
        for (int k = k0; k < DIN_; k += 32)
            slab[c * 1032 + k] = (_Float16)Win[(size_t)k * N_ + wc];
        __syncthreads();
        if (wave == p) {
            #pragma unroll
            for (int kb = 0; kb < 8; ++kb)
                winf[kb] = *(const half8*)&slab[l15 * 1032 + kb * 32 + quad * 8];
        }
        __syncthreads();
    }

    // ---- s[:,0,:] = 0 for this block's 16r x 128c slice
    #pragma unroll
    for (int i = 0; i < 4; ++i) {
        int e = i * 512 + tid;
        int r = e >> 7, c = e & 127;
        s_out[(size_t)(bs * 16 + r) * T_ * N_ + cg * 128 + c] = 0.0f;
    }

    // ---- u_1 = X[:,0,:] @ Win
    f32x4 u = {0.f, 0.f, 0.f, 0.f};
    {
        const float* xp = X + (size_t)arow * T_ * DIN_ + quad * 8;
        #pragma unroll
        for (int kb = 0; kb < 8; ++kb) {
            float4 x0 = *(const float4*)(xp + kb * 32);
            float4 x1 = *(const float4*)(xp + kb * 32 + 4);
            u = __builtin_amdgcn_mfma_f32_16x16x32_f16(cvt8(x0, x1), winf[kb], u, 0, 0, 0);
        }
    }

    // producer packet addressing: element (m=row, col) lives at half index
    //   h = (col>>5)*512 + ((col>>3)&3)*128 + m*8 + (col&7),  m = quad*4 + r
    // packet index = h/2 over the even col of the (colE, colE+1) pair.
    const int col   = col0 + l15;
    const int colE  = col & ~1;
    const int pidx0 = ((colE >> 5) * 512 + ((colE >> 3) & 3) * 128
                       + quad * 32 + (colE & 7)) >> 1;
    const bool odd  = (l15 & 1) != 0;
    const int rbase = odd ? 2 : 0;        // even l15 handles rows r=0,1; odd r=2,3

    ull v[16];                            // pre-issued consumer packet loads
    const ull* rp = exch;                 // buffer the preload came from

    for (int t = 1; t < T_; ++t) {
        f32x4 acc0 = u;
        f32x4 acc1 = {0.f, 0.f, 0.f, 0.f};
        f32x4 acc2 = {0.f, 0.f, 0.f, 0.f};
        f32x4 acc3 = {0.f, 0.f, 0.f, 0.f};

        if (t >= 2) {
            // ---- spin directly on self-tagged data (reload-all-until-fresh;
            // values are stable once their tag matches, see header comment)
            const unsigned want = (unsigned)(t - 1);
            for (;;) {
                bool ok = true;
                #pragma unroll
                for (int k = 0; k < 16; ++k)
                    ok &= ((unsigned)(v[k] >> 32) == want);
                if (ok) break;
                #pragma unroll
                for (int k = 0; k < 16; ++k)
                    v[k] = __hip_atomic_load(&rp[tid + 512 * k],
                                             __ATOMIC_RELAXED, __HIP_MEMORY_SCOPE_AGENT);
            }
            // ---- stage fp16 payload to LDS (linear u32 writes, 2-way alias = free)
            unsigned int* lp = (unsigned int*)slab;
            #pragma unroll
            for (int k = 0; k < 16; ++k)
                lp[tid + 512 * k] = (unsigned int)v[k];
            // raw barrier: only LDS visibility needed — do NOT drain vmcnt
            asm volatile("s_waitcnt lgkmcnt(0)\n\ts_barrier" ::: "memory");

            #pragma unroll
            for (int kb = 0; kb < 32; ++kb) {
                half8 a = *(const half8*)&slab[kb * 512 + lane * 8];
                if ((kb & 3) == 0)      acc0 = __builtin_amdgcn_mfma_f32_16x16x32_f16(a, wf[kb], acc0, 0, 0, 0);
                else if ((kb & 3) == 1) acc1 = __builtin_amdgcn_mfma_f32_16x16x32_f16(a, wf[kb], acc1, 0, 0, 0);
                else if ((kb & 3) == 2) acc2 = __builtin_amdgcn_mfma_f32_16x16x32_f16(a, wf[kb], acc2, 0, 0, 0);
                else                    acc3 = __builtin_amdgcn_mfma_f32_16x16x32_f16(a, wf[kb], acc3, 0, 0, 0);
            }
        }

        float v4[4];
        #pragma unroll
        for (int r = 0; r < 4; ++r)
            v4[r] = fast_tanh(acc0[r] + acc1[r] + acc2[r] + acc3[r]);

        // ---- critical-path publish: pair adjacent cols via shfl, 2 x 8B
        // self-tagged atomic stores, NO drain, NO flag.
        ull* eb = exch + (size_t)(bs * 2 + (t & 1)) * 8192;
        {
            float q0 = __shfl_xor(v4[0], 1);
            float q1 = __shfl_xor(v4[1], 1);
            float q2 = __shfl_xor(v4[2], 1);
            float q3 = __shfl_xor(v4[3], 1);
            // value at even col / odd col for rows rbase, rbase+1 (static selects,
            // no runtime-indexed arrays -> stays in VGPRs)
            float e0 = odd ? q2 : v4[0];
            float o0 = odd ? v4[2] : q0;
            float e1 = odd ? q3 : v4[1];
            float o1 = odd ? v4[3] : q1;
            const ull tagbits = (ull)(unsigned)t << 32;
            __hip_atomic_store(&eb[pidx0 + rbase * 4],
                               (ull)pack2h(e0, o0) | tagbits,
                               __ATOMIC_RELAXED, __HIP_MEMORY_SCOPE_AGENT);
            __hip_atomic_store(&eb[pidx0 + rbase * 4 + 4],
                               (ull)pack2h(e1, o1) | tagbits,
                               __ATOMIC_RELAXED, __HIP_MEMORY_SCOPE_AGENT);
        }

        // ---- pre-issue next step's consumer loads (overlap with tail work)
        if (t < T_ - 1) {
            rp = eb;
            #pragma unroll
            for (int k = 0; k < 16; ++k)
                v[k] = __hip_atomic_load(&rp[tid + 512 * k],
                                         __ATOMIC_RELAXED, __HIP_MEMORY_SCOPE_AGENT);
        }

        // ---- off critical path: fp32 s_out + u_{t+1}
        #pragma unroll
        for (int r = 0; r < 4; ++r)
            s_out[(size_t)(crow + r) * T_ * N_ + (size_t)t * N_ + col] = v4[r];

        f32x4 un = {0.f, 0.f, 0.f, 0.f};
        if (t < T_ - 1) {
            const float* xp = X + ((size_t)arow * T_ + t) * DIN_ + quad * 8;
            #pragma unroll
            for (int kb = 0; kb < 8; ++kb) {
                float4 x0 = *(const float4*)(xp + kb * 32);
                float4 x1 = *(const float4*)(xp + kb * 32 + 4);
                un = __builtin_amdgcn_mfma_f32_16x16x32_f16(cvt8(x0, x1), winf[kb], un, 0, 0, 0);
            }
        }
        u = un;
    }
}

// ---------------------------------------------------------------------------
// Epilogue: out = s @ Wout + bout.  M=32768, N=128, K=1024.
// ---------------------------------------------------------------------------
__global__ __launch_bounds__(256, 2) void out_gemm(
    const float* __restrict__ s_in,   // [B*T][N]
    const float* __restrict__ Wout,   // [N][O]
    const float* __restrict__ bout,   // [O]
    float* __restrict__ outp)         // [B*T][O]
{
    const int m0   = blockIdx.x * 128;
    const int tid  = threadIdx.x;
    const int wave = tid >> 6;
    const int lane = tid & 63;
    const int l15  = lane & 15;
    const int quad = lane >> 4;

    __shared__ _Float16 WoT[128][40];

    f32x4 acc[2][8];
    #pragma unroll
    for (int mf = 0; mf < 2; ++mf)
        #pragma unroll
        for (int nt = 0; nt < 8; ++nt) acc[mf][nt] = f32x4{0.f, 0.f, 0.f, 0.f};
    float bv[8];
    #pragma unroll
    for (int nt = 0; nt < 8; ++nt) bv[nt] = bout[nt * 16 + l15];

    for (int kb = 0; kb < 32; ++kb) {
        __syncthreads();
        #pragma unroll
        for (int i = 0; i < 16; ++i) {
            int e = i * 256 + tid;
            int c = e & 127, kk = e >> 7;
            WoT[c][kk] = (_Float16)Wout[(size_t)(kb * 32 + kk) * O_ + c];
        }
        __syncthreads();

        #pragma unroll
        for (int mf = 0; mf < 2; ++mf) {
            const float* ap = s_in + (size_t)(m0 + wave * 32 + mf * 16 + l15) * N_ + kb * 32 + quad * 8;
            float4 a0 = *(const float4*)ap;
            float4 a1 = *(const float4*)(ap + 4);
            half8 a = cvt8(a0, a1);
            #pragma unroll
            for (int nt = 0; nt < 8; ++nt) {
                half8 b = *(const half8*)&WoT[nt * 16 + l15][quad * 8];
                acc[mf][nt] = __builtin_amdgcn_mfma_f32_16x16x32_f16(a, b, acc[mf][nt], 0, 0, 0);
            }
        }
    }

    #pragma unroll
    for (int mf = 0; mf < 2; ++mf) {
        float* op = outp + (size_t)(m0 + wave * 32 + mf * 16 + quad * 4) * O_ + l15;
        #pragma unroll
        for (int nt = 0; nt < 8; ++nt)
            #pragma unroll
            for (int r = 0; r < 4; ++r)
                op[(size_t)r * O_ + nt * 16] = acc[mf][nt][r] + bv[nt];
    }
}

extern "C" void kernel_launch(void* const* d_in, const int* in_sizes, int n_in,
                              void* d_out, int out_size, void* d_ws, size_t ws_size,
                              hipStream_t stream) {
    const float* X    = (const float*)d_in[0];   // [64][512][256]
    const float* Win  = (const float*)d_in[1];   // [256][1024]
    const float* W    = (const float*)d_in[2];   // [1024][1024]
    const float* Wout = (const float*)d_in[3];   // [1024][128]
    const float* bout = (const float*)d_in[4];   // [128]

    float* s_out = (float*)d_out;                 // [64][512][1024]
    float* outp  = s_out + (size_t)B_ * T_ * N_;  // [64][512][128]

    ull* exch = (ull*)d_ws;                       // [4][2][8192] packets = 512 KB

    init_kernel<<<64, 1024, 0, stream>>>(exch);
    rnn_kernel<<<32, 512, 0, stream>>>(X, W, Win, s_out, exch);
    out_gemm<<<256, 256, 0, stream>>>(s_out, Wout, bout, outp);
}

// Round 2
// 3219.419 us; speedup vs baseline: 1.5279x; 1.5279x over previous
//
#include <hip/hip_runtime.h>

// Problem constants
#define B_ 64
#define T_ 512
#define DIN_ 256
#define N_ 1024
#define O_ 128

using half8 = __attribute__((ext_vector_type(8))) _Float16;
using f32x4 = __attribute__((ext_vector_type(4))) float;
typedef unsigned long long ull;

__device__ __forceinline__ half8 cvt8(float4 a, float4 b) {
    half8 h;
    h[0] = (_Float16)a.x; h[1] = (_Float16)a.y; h[2] = (_Float16)a.z; h[3] = (_Float16)a.w;
    h[4] = (_Float16)b.x; h[5] = (_Float16)b.y; h[6] = (_Float16)b.z; h[7] = (_Float16)b.w;
    return h;
}

__device__ __forceinline__ float fast_tanh(float x) {
    float ax = __builtin_fabsf(x);
    float e  = __expf(-2.0f * ax);
    float r  = __fdividef(1.0f - e, 1.0f + e);
    return x < 0.0f ? -r : r;
}

// ---------------------------------------------------------------------------
// Zero the 256 per-wave sentinels (only 4*64 used). Sentinels are monotone
// step tags; 0 never satisfies want >= 1, so no stale-accept across launches.
// ---------------------------------------------------------------------------
__global__ void init_kernel(unsigned int* sent) {
    sent[threadIdx.x] = 0u;
}

// ---------------------------------------------------------------------------
// Persistent recurrence: 32 blocks = 4 batch-slabs (bs) x 8 col-groups (cg).
// Block = 512 threads (8 waves), 16 batch rows x 128 cols; wave w owns 16 cols
// with its W slab (128 VGPRs fp16) + Win slab (32 VGPRs) register-resident.
//
// Sync protocol (R2): PER-WAVE SENTINELS, no block-wide drain, no flag tid0.
//   producer wave: 4 x 2B data stores (agent) -> s_waitcnt vmcnt(0) [waits
//   only its own 4 stores; all earlier vmem was consumed by the u-GEMM data
//   dependency] -> lane0 stores sent[cg*8+wave] = t. The 8 waves publish in
//   parallel; the old __syncthreads barrier-gather + full-block drain + a
//   single serialized flag store are gone from the critical path.
//   consumer: spins on the 64 sentinels of its bs group with ONE coalesced
//   4B/lane load; proceeds when __all(sent >= t-1) (>= because fast
//   producers may already have published t). Then loads the fp16 slab ONCE
//   (8 x 8B/thread). Monotone tags + the consume-gates-produce chain prove
//   a sentinel's visibility implies its wave's data is at the coherence
//   point (producer vmcnt(0)-ed its data stores before the sentinel), and
//   that no wanted location can be overwritten (a block writes buffer t&1
//   at step t only after every block consumed step t-1).
// In-loop barriers are raw s_barrier (WAR: slab writes vs previous step's
// ds_reads -- those completed before the MFMAs that consumed them) and
// lgkmcnt(0)+s_barrier (RAW: slab writes visible before ds_reads). No vmcnt
// drain anywhere in the loop.
// Exchange layout (R0-verified): fp16, MFMA A-fragment order
// (addr_half = kb*512 + lane*8 + j); consumer staging is linear ull copies
// (2-way bank alias = free) then conflict-free ds_read_b128.
// ---------------------------------------------------------------------------
__global__ __launch_bounds__(512, 1) void rnn_kernel(
    const float* __restrict__ X,      // [B][T][DIN]
    const float* __restrict__ W,      // [N][N]
    const float* __restrict__ Win,    // [DIN][N]
    float* __restrict__ s_out,        // [B][T][N]
    _Float16* __restrict__ exch,      // [4][2][16384] fp16, frag order
    unsigned int* __restrict__ sent)  // [4][64] per-wave sentinels
{
    const int bs   = blockIdx.x & 3;
    const int cg   = blockIdx.x >> 2;     // 0..7
    const int tid  = threadIdx.x;
    const int wave = tid >> 6;            // 0..7
    const int lane = tid & 63;
    const int l15  = lane & 15;
    const int quad = lane >> 4;
    const int col0 = cg * 128 + wave * 16;
    const int arow = bs * 16 + l15;       // A-frag batch row
    const int crow = bs * 16 + quad * 4;  // C-frag base batch row

    __shared__ _Float16 slab[16 * 1032];  // W/Win transpose staging + step slab

    // ---- one-time: W B-fragments (8 passes, one per wave)
    half8 wf[32];
    for (int p = 0; p < 8; ++p) {
        const int c = tid & 15, k0 = tid >> 4;
        const int wc = cg * 128 + p * 16 + c;
        for (int k = k0; k < N_; k += 32)
            slab[c * 1032 + k] = (_Float16)W[(size_t)k * N_ + wc];
        __syncthreads();
        if (wave == p) {
            #pragma unroll
            for (int kb = 0; kb < 32; ++kb)
                wf[kb] = *(const half8*)&slab[l15 * 1032 + kb * 32 + quad * 8];
        }
        __syncthreads();
    }
    // ---- one-time: Win B-fragments
    half8 winf[8];
    for (int p = 0; p < 8; ++p) {
        const int c = tid & 15, k0 = tid >> 4;
        const int wc = cg * 128 + p * 16 + c;
        for (int k = k0; k < DIN_; k += 32)
            slab[c * 1032 + k] = (_Float16)Win[(size_t)k * N_ + wc];
        __syncthreads();
        if (wave == p) {
            #pragma unroll
            for (int kb = 0; kb < 8; ++kb)
                winf[kb] = *(const half8*)&slab[l15 * 1032 + kb * 32 + quad * 8];
        }
        __syncthreads();
    }

    // ---- s[:,0,:] = 0 for this block's 16r x 128c slice
    #pragma unroll
    for (int i = 0; i < 4; ++i) {
        int e = i * 512 + tid;
        int r = e >> 7, c = e & 127;
        s_out[(size_t)(bs * 16 + r) * T_ * N_ + cg * 128 + c] = 0.0f;
    }

    // ---- u_1 = X[:,0,:] @ Win
    f32x4 u = {0.f, 0.f, 0.f, 0.f};
    {
        const float* xp = X + (size_t)arow * T_ * DIN_ + quad * 8;
        #pragma unroll
        for (int kb = 0; kb < 8; ++kb) {
            float4 x0 = *(const float4*)(xp + kb * 32);
            float4 x1 = *(const float4*)(xp + kb * 32 + 4);
            u = __builtin_amdgcn_mfma_f32_16x16x32_f16(cvt8(x0, x1), winf[kb], u, 0, 0, 0);
        }
    }

    // producer exchange address (frag order): element (m=row, col):
    // addr_half = (col>>5)*512 + ((col>>3)&3)*128 + m*8 + (col&7); m = quad*4+r
    const int col   = col0 + l15;
    const int ebase = (col >> 5) * 512 + ((col >> 3) & 3) * 128 + quad * 32 + (col & 7);

    unsigned int* sp = sent + bs * 64;    // 64 sentinels for this bs group
    const int mysent = cg * 8 + wave;

    for (int t = 1; t < T_; ++t) {
        f32x4 acc0 = u;
        f32x4 acc1 = {0.f, 0.f, 0.f, 0.f};
        f32x4 acc2 = {0.f, 0.f, 0.f, 0.f};
        f32x4 acc3 = {0.f, 0.f, 0.f, 0.f};

        if (t >= 2) {
            // ---- cheap detect: one coalesced 4B/lane sentinel load per round
            const unsigned want = (unsigned)(t - 1);
            for (;;) {
                unsigned v = __hip_atomic_load(&sp[lane], __ATOMIC_RELAXED,
                                               __HIP_MEMORY_SCOPE_AGENT);
                if (__all((int)(v >= want))) break;
            }

            // ---- one-shot data load: 8 x 8B/thread = full 16x1024 fp16 slab
            const ull* ep = (const ull*)(exch + (size_t)(bs * 2 + ((t - 1) & 1)) * 16384);
            ull r0 = __hip_atomic_load(&ep[tid],        __ATOMIC_RELAXED, __HIP_MEMORY_SCOPE_AGENT);
            ull r1 = __hip_atomic_load(&ep[tid + 512],  __ATOMIC_RELAXED, __HIP_MEMORY_SCOPE_AGENT);
            ull r2 = __hip_atomic_load(&ep[tid + 1024], __ATOMIC_RELAXED, __HIP_MEMORY_SCOPE_AGENT);
            ull r3 = __hip_atomic_load(&ep[tid + 1536], __ATOMIC_RELAXED, __HIP_MEMORY_SCOPE_AGENT);
            ull r4 = __hip_atomic_load(&ep[tid + 2048], __ATOMIC_RELAXED, __HIP_MEMORY_SCOPE_AGENT);
            ull r5 = __hip_atomic_load(&ep[tid + 2560], __ATOMIC_RELAXED, __HIP_MEMORY_SCOPE_AGENT);
            ull r6 = __hip_atomic_load(&ep[tid + 3072], __ATOMIC_RELAXED, __HIP_MEMORY_SCOPE_AGENT);
            ull r7 = __hip_atomic_load(&ep[tid + 3584], __ATOMIC_RELAXED, __HIP_MEMORY_SCOPE_AGENT);

            // WAR barrier: previous step's ds_reads across the block are done
            // (their MFMAs consumed them); loads above overlap this barrier.
            asm volatile("s_barrier" ::: "memory");

            ull* lp = (ull*)slab;
            lp[tid]        = r0;
            lp[tid + 512]  = r1;
            lp[tid + 1024] = r2;
            lp[tid + 1536] = r3;
            lp[tid + 2048] = r4;
            lp[tid + 2560] = r5;
            lp[tid + 3072] = r6;
            lp[tid + 3584] = r7;
            // RAW barrier: LDS visibility only — no vmcnt drain
            asm volatile("s_waitcnt lgkmcnt(0)\n\ts_barrier" ::: "memory");

            #pragma unroll
            for (int kb = 0; kb < 32; ++kb) {
                half8 a = *(const half8*)&slab[kb * 512 + lane * 8];
                if ((kb & 3) == 0)      acc0 = __builtin_amdgcn_mfma_f32_16x16x32_f16(a, wf[kb], acc0, 0, 0, 0);
                else if ((kb & 3) == 1) acc1 = __builtin_amdgcn_mfma_f32_16x16x32_f16(a, wf[kb], acc1, 0, 0, 0);
                else if ((kb & 3) == 2) acc2 = __builtin_amdgcn_mfma_f32_16x16x32_f16(a, wf[kb], acc2, 0, 0, 0);
                else                    acc3 = __builtin_amdgcn_mfma_f32_16x16x32_f16(a, wf[kb], acc3, 0, 0, 0);
            }
        }

        float v4[4];
        #pragma unroll
        for (int r = 0; r < 4; ++r)
            v4[r] = fast_tanh(acc0[r] + acc1[r] + acc2[r] + acc3[r]);

        // ---- critical-path publish: 4 x 2B agent stores, then wait ONLY
        // those (vmcnt already 0 here), then per-wave sentinel. No barrier.
        _Float16* eb = exch + (size_t)(bs * 2 + (t & 1)) * 16384;
        #pragma unroll
        for (int r = 0; r < 4; ++r) {
            union { _Float16 h; unsigned short s; } cv;
            cv.h = (_Float16)v4[r];
            __hip_atomic_store((unsigned short*)(eb + ebase + r * 8), cv.s,
                               __ATOMIC_RELAXED, __HIP_MEMORY_SCOPE_AGENT);
        }
        asm volatile("s_waitcnt vmcnt(0)" ::: "memory");
        if (lane == 0)
            __hip_atomic_store(&sp[mysent], (unsigned int)t,
                               __ATOMIC_RELAXED, __HIP_MEMORY_SCOPE_AGENT);

        // ---- off critical path: fp32 s_out + u_{t+1}
        #pragma unroll
        for (int r = 0; r < 4; ++r)
            s_out[(size_t)(crow + r) * T_ * N_ + (size_t)t * N_ + col] = v4[r];

        f32x4 un = {0.f, 0.f, 0.f, 0.f};
        if (t < T_ - 1) {
            const float* xp = X + ((size_t)arow * T_ + t) * DIN_ + quad * 8;
            #pragma unroll
            for (int kb = 0; kb < 8; ++kb) {
                float4 x0 = *(const float4*)(xp + kb * 32);
                float4 x1 = *(const float4*)(xp + kb * 32 + 4);
                un = __builtin_amdgcn_mfma_f32_16x16x32_f16(cvt8(x0, x1), winf[kb], un, 0, 0, 0);
            }
        }
        u = un;
    }
}

// ---------------------------------------------------------------------------
// Epilogue: out = s @ Wout + bout.  M=32768, N=128, K=1024.
// ---------------------------------------------------------------------------
__global__ __launch_bounds__(256, 2) void out_gemm(
    const float* __restrict__ s_in,   // [B*T][N]
    const float* __restrict__ Wout,   // [N][O]
    const float* __restrict__ bout,   // [O]
    float* __restrict__ outp)         // [B*T][O]
{
    const int m0   = blockIdx.x * 128;
    const int tid  = threadIdx.x;
    const int wave = tid >> 6;
    const int lane = tid & 63;
    const int l15  = lane & 15;
    const int quad = lane >> 4;

    __shared__ _Float16 WoT[128][40];

    f32x4 acc[2][8];
    #pragma unroll
    for (int mf = 0; mf < 2; ++mf)
        #pragma unroll
        for (int nt = 0; nt < 8; ++nt) acc[mf][nt] = f32x4{0.f, 0.f, 0.f, 0.f};
    float bv[8];
    #pragma unroll
    for (int nt = 0; nt < 8; ++nt) bv[nt] = bout[nt * 16 + l15];

    for (int kb = 0; kb < 32; ++kb) {
        __syncthreads();
        #pragma unroll
        for (int i = 0; i < 16; ++i) {
            int e = i * 256 + tid;
            int c = e & 127, kk = e >> 7;
            WoT[c][kk] = (_Float16)Wout[(size_t)(kb * 32 + kk) * O_ + c];
        }
        __syncthreads();

        #pragma unroll
        for (int mf = 0; mf < 2; ++mf) {
            const float* ap = s_in + (size_t)(m0 + wave * 32 + mf * 16 + l15) * N_ + kb * 32 + quad * 8;
            float4 a0 = *(const float4*)ap;
            float4 a1 = *(const float4*)(ap + 4);
            half8 a = cvt8(a0, a1);
            #pragma unroll
            for (int nt = 0; nt < 8; ++nt) {
                half8 b = *(const half8*)&WoT[nt * 16 + l15][quad * 8];
                acc[mf][nt] = __builtin_amdgcn_mfma_f32_16x16x32_f16(a, b, acc[mf][nt], 0, 0, 0);
            }
        }
    }

    #pragma unroll
    for (int mf = 0; mf < 2; ++mf) {
        float* op = outp + (size_t)(m0 + wave * 32 + mf * 16 + quad * 4) * O_ + l15;
        #pragma unroll
        for (int nt = 0; nt < 8; ++nt)
            #pragma unroll
            for (int r = 0; r < 4; ++r)
                op[(size_t)r * O_ + nt * 16] = acc[mf][nt][r] + bv[nt];
    }
}

extern "C" void kernel_launch(void* const* d_in, const int* in_sizes, int n_in,
                              void* d_out, int out_size, void* d_ws, size_t ws_size,
                              hipStream_t stream) {
    const float* X    = (const float*)d_in[0];   // [64][512][256]
    const float* Win  = (const float*)d_in[1];   // [256][1024]
    const float* W    = (const float*)d_in[2];   // [1024][1024]
    const float* Wout = (const float*)d_in[3];   // [1024][128]
    const float* bout = (const float*)d_in[4];   // [128]

    float* s_out = (float*)d_out;                 // [64][512][1024]
    float* outp  = s_out + (size_t)B_ * T_ * N_;  // [64][512][128]

    unsigned int* sent = (unsigned int*)d_ws;               // 256 uints
    _Float16* exch = (_Float16*)((char*)d_ws + 4096);       // 256 KB

    init_kernel<<<1, 256, 0, stream>>>(sent);
    rnn_kernel<<<32, 512, 0, stream>>>(X, W, Win, s_out, exch, sent);
    out_gemm<<<256, 256, 0, stream>>>(s_out, Wout, bout, outp);
}